// Round 10
// baseline (536.780 us; speedup 1.0000x reference)
//
#include <hip/hip_runtime.h>
#include <math.h>

#define S 13824          // 24*24*24
#define RT 216           // tokens per region (6^3)
#define SCALE 0.08838834764831845f  // 128^-0.5

// ---------------- 1x1 conv (channel matmul): out[o][s] = sum_c w[o][c]*in[c][s] + b[o]
// round-2 proven version: 64-col tiles, 216 blocks, 36us(qkv)/23.5us(out)
__global__ __launch_bounds__(256) void proj_kernel(
    const float* __restrict__ in, const float* __restrict__ w,
    const float* __restrict__ bias, float* __restrict__ outp, int OC) {
  __shared__ float xs[128][64];
  const int tid = threadIdx.x;
  const int sbase = blockIdx.x * 64;
  for (int i = tid; i < 128 * 64; i += 256)
    xs[i >> 6][i & 63] = in[(size_t)(i >> 6) * S + sbase + (i & 63)];
  __syncthreads();
  const int sl = tid & 63;
  const int wv = tid >> 6;
  const int ogN = OC >> 4;
  for (int og = 0; og < ogN; ++og) {
    const int o = og * 16 + wv * 4;
    const float4* w0 = (const float4*)(w + (size_t)o * 128);
    const float4* w1 = w0 + 32;
    const float4* w2 = w0 + 64;
    const float4* w3 = w0 + 96;
    float a0 = 0.f, a1 = 0.f, a2 = 0.f, a3 = 0.f;
#pragma unroll 8
    for (int c4 = 0; c4 < 32; ++c4) {
      float4 f0 = w0[c4], f1 = w1[c4], f2 = w2[c4], f3 = w3[c4];
      float x0 = xs[c4 * 4 + 0][sl], x1 = xs[c4 * 4 + 1][sl];
      float x2 = xs[c4 * 4 + 2][sl], x3 = xs[c4 * 4 + 3][sl];
      a0 += f0.x * x0 + f0.y * x1 + f0.z * x2 + f0.w * x3;
      a1 += f1.x * x0 + f1.y * x1 + f1.z * x2 + f1.w * x3;
      a2 += f2.x * x0 + f2.y * x1 + f2.z * x2 + f2.w * x3;
      a3 += f3.x * x0 + f3.y * x1 + f3.z * x2 + f3.w * x3;
    }
    size_t base = (size_t)o * S + sbase + sl;
    outp[base]         = a0 + bias[o + 0];
    outp[base + S]     = a1 + bias[o + 1];
    outp[base + 2 * S] = a2 + bias[o + 2];
    outp[base + 3 * S] = a3 + bias[o + 3];
  }
}

// ---------------- region means of q and k (deterministic shuffle-tree reduce)
__global__ __launch_bounds__(256) void rmean_kernel(
    const float* __restrict__ qk, float* __restrict__ qr, float* __restrict__ kr) {
  const int n = blockIdx.x;
  const int tid = threadIdx.x, lane = tid & 63, wv = tid >> 6;
  const int rh = (n >> 4) * 6, rw = ((n >> 2) & 3) * 6, rd = (n & 3) * 6;
  int soff[4];
#pragma unroll
  for (int i = 0; i < 4; ++i) {
    int vx = lane + i * 64;
    if (vx < RT) {
      int p = vx / 36, qq = (vx / 6) % 6, u = vx % 6;
      soff[i] = (rh + p) * 576 + (rw + qq) * 24 + (rd + u);
    } else soff[i] = -1;
  }
  for (int ci = 0; ci < 64; ++ci) {
    int ch = wv + ci * 4;  // 0..255
    const float* src = qk + (size_t)ch * S;
    float ssum = 0.f;
#pragma unroll
    for (int i = 0; i < 4; ++i)
      if (soff[i] >= 0) ssum += src[soff[i]];
    for (int off = 32; off > 0; off >>= 1)
      ssum += __shfl_xor(ssum, off);
    if (lane == 0) {
      if (ch < 128) qr[n * 128 + ch] = ssum * (1.f / 216.f);
      else          kr[n * 128 + (ch - 128)] = ssum * (1.f / 216.f);
    }
  }
}

// ---------------- routing: top-4 with low-index tie-break (matches lax.top_k)
__global__ __launch_bounds__(64) void route_kernel(
    const float* __restrict__ qr, const float* __restrict__ kr, int* __restrict__ idxb) {
  const int n = blockIdx.x;
  const int t = threadIdx.x;  // key region
  float acc = 0.f;
  for (int c = 0; c < 128; ++c) acc += qr[n * 128 + c] * kr[t * 128 + c];
  float val = acc;
  int id = t;
  for (int j = 0; j < 4; ++j) {
    float bv = val;
    int bi = id;
    for (int off = 32; off > 0; off >>= 1) {
      float ov = __shfl_xor(bv, off);
      int oi = __shfl_xor(bi, off);
      if (ov > bv || (ov == bv && oi < bi)) { bv = ov; bi = oi; }
    }
    if (t == 0) idxb[n * 4 + j] = bi;
    if (id == bi) val = -INFINITY;
  }
}

// ---------------- attention: one 512-thread block per (region n, head mh).
// Two 4-wave halves each process 2 of 4 top-k regions, flash-merge at end.
// waves_per_eu(4,4): LDS (138KB/CU) caps us at 2 blocks/CU = 4 waves/SIMD
// anyway; pinning max=4 stops the allocator targeting 8 waves (64 VGPR) and
// spilling (rounds 4/6/9: FETCH 78-98MB, WRITE 13-29MB of pure scratch).
__global__ __attribute__((amdgpu_flat_work_group_size(512, 512), amdgpu_waves_per_eu(4, 4)))
void attn_kernel(
    const float* __restrict__ qkv, const int* __restrict__ idxb, float* __restrict__ go) {
  __shared__ __align__(16) float ks[2][RT][20];
  __shared__ __align__(16) float vs[2][RT][20];
  const float* q = qkv;
  const float* k = qkv + (size_t)128 * S;
  const float* v = qkv + (size_t)256 * S;
  const int n = blockIdx.x, mh = blockIdx.y;
  const int tid = threadIdx.x;
  const int h = tid >> 8;        // which half (0/1) -> kv regions {0,1} or {2,3}
  const int qi = tid & 255;      // query token within region
  const int rh = (n >> 4) * 6, rw = ((n >> 2) & 3) * 6, rd = (n & 3) * 6;
  const bool active = qi < RT;
  float ql[16];
  int sq = 0;
  if (active) {
    int p = qi / 36, qq = (qi / 6) % 6, u = qi % 6;
    sq = (rh + p) * 576 + (rw + qq) * 24 + (rd + u);
#pragma unroll
    for (int d = 0; d < 16; ++d)
      ql[d] = q[(size_t)(mh * 16 + d) * S + sq] * SCALE;
  }
  float m = -INFINITY, denom = 0.f;
  float o[16];
#pragma unroll
  for (int d = 0; d < 16; ++d) o[d] = 0.f;

  for (int j = 0; j < 2; ++j) {
    const int r = idxb[n * 4 + h * 2 + j];
    const int gh = (r >> 4) * 6, gw = ((r >> 2) & 3) * 6, gd = (r & 3) * 6;
    __syncthreads();
    for (int i = qi; i < RT * 16; i += 256) {
      int t = i % RT, d = i / RT;
      int p = t / 36, qq = (t / 6) % 6, u = t % 6;
      int s = (gh + p) * 576 + (gw + qq) * 24 + (gd + u);
      ks[h][t][d] = k[(size_t)(mh * 16 + d) * S + s];
      vs[h][t][d] = v[(size_t)(mh * 16 + d) * S + s];
    }
    __syncthreads();
    if (active) {
      for (int key0 = 0; key0 < RT; key0 += 4) {
        float dot[4];
#pragma unroll
        for (int kk = 0; kk < 4; ++kk) {
          const float4* kp = (const float4*)&ks[h][key0 + kk][0];
          float4 k0 = kp[0], k1 = kp[1], k2 = kp[2], k3 = kp[3];
          dot[kk] = ql[0] * k0.x + ql[1] * k0.y + ql[2] * k0.z + ql[3] * k0.w
                  + ql[4] * k1.x + ql[5] * k1.y + ql[6] * k1.z + ql[7] * k1.w
                  + ql[8] * k2.x + ql[9] * k2.y + ql[10] * k2.z + ql[11] * k2.w
                  + ql[12] * k3.x + ql[13] * k3.y + ql[14] * k3.z + ql[15] * k3.w;
        }
        float cmax = fmaxf(fmaxf(dot[0], dot[1]), fmaxf(dot[2], dot[3]));
        float mnew = fmaxf(m, cmax);
        float sc = __expf(m - mnew);   // m=-inf first time -> 0, state is zero anyway
        m = mnew;
        denom *= sc;
#pragma unroll
        for (int d = 0; d < 16; ++d) o[d] *= sc;
#pragma unroll
        for (int kk = 0; kk < 4; ++kk) dot[kk] = __expf(dot[kk] - m);
#pragma unroll
        for (int kk = 0; kk < 4; ++kk) denom += dot[kk];
#pragma unroll
        for (int kk = 0; kk < 4; ++kk) {
          const float4* vp = (const float4*)&vs[h][key0 + kk][0];
          float4 v0 = vp[0], v1 = vp[1], v2 = vp[2], v3 = vp[3];
          float p = dot[kk];
          o[0] += p * v0.x;  o[1] += p * v0.y;  o[2] += p * v0.z;  o[3] += p * v0.w;
          o[4] += p * v1.x;  o[5] += p * v1.y;  o[6] += p * v1.z;  o[7] += p * v1.w;
          o[8] += p * v2.x;  o[9] += p * v2.y;  o[10] += p * v2.z; o[11] += p * v2.w;
          o[12] += p * v3.x; o[13] += p * v3.y; o[14] += p * v3.z; o[15] += p * v3.w;
        }
      }
    }
  }
  // flash-merge the two halves (reuse ks storage as scratch)
  __syncthreads();
  float* mb = (float*)ks;
  if (h == 1 && active) {
    mb[qi * 18 + 0] = m;
    mb[qi * 18 + 1] = denom;
#pragma unroll
    for (int d = 0; d < 16; ++d) mb[qi * 18 + 2 + d] = o[d];
  }
  __syncthreads();
  if (h == 0 && active) {
    float m1 = mb[qi * 18 + 0], d1 = mb[qi * 18 + 1];
    float M = fmaxf(m, m1);
    float s0 = __expf(m - M), s1 = __expf(m1 - M);
    float inv = 1.f / (denom * s0 + d1 * s1);
#pragma unroll
    for (int d = 0; d < 16; ++d)
      go[(size_t)(mh * 16 + d) * S + sq] = (o[d] * s0 + mb[qi * 18 + 2 + d] * s1) * inv;
  }
}

// ---------------- lepe: depthwise 3x3x3 conv on v, accumulated into go
// round-2 proven version (16.8us)
__global__ __launch_bounds__(256) void lepe_kernel(
    const float* __restrict__ v, const float* __restrict__ wl,
    const float* __restrict__ bl, float* __restrict__ go) {
  const int c = blockIdx.y;
  const int s = blockIdx.x * 256 + threadIdx.x;
  const int h = s / 576, w = (s / 24) % 24, d = s % 24;
  const float* vp = v + (size_t)c * S;
  float wreg[27];
#pragma unroll
  for (int i = 0; i < 27; ++i) wreg[i] = wl[c * 27 + i];
  float acc = bl[c];
#pragma unroll
  for (int a = 0; a < 3; ++a) {
    int hh = h + a - 1;
    if (hh < 0 || hh >= 24) continue;
#pragma unroll
    for (int b = 0; b < 3; ++b) {
      int ww = w + b - 1;
      if (ww < 0 || ww >= 24) continue;
#pragma unroll
      for (int e = 0; e < 3; ++e) {
        int dd = d + e - 1;
        if (dd < 0 || dd >= 24) continue;
        acc += vp[hh * 576 + ww * 24 + dd] * wreg[a * 9 + b * 3 + e];
      }
    }
  }
  go[(size_t)c * S + s] += acc;
}

extern "C" void kernel_launch(void* const* d_in, const int* in_sizes, int n_in,
                              void* d_out, int out_size, void* d_ws, size_t ws_size,
                              hipStream_t stream) {
  const float* x      = (const float*)d_in[0];
  const float* w_qkv  = (const float*)d_in[1];
  const float* b_qkv  = (const float*)d_in[2];
  const float* w_lepe = (const float*)d_in[3];
  const float* b_lepe = (const float*)d_in[4];
  const float* w_out  = (const float*)d_in[5];
  const float* b_out  = (const float*)d_in[6];
  float* out = (float*)d_out;
  float* ws  = (float*)d_ws;

  float* qkv  = ws;                        // 384*13824
  float* go   = qkv + (size_t)384 * S;     // 128*13824
  float* qr   = go + (size_t)128 * S;      // 64*128
  float* kr   = qr + 8192;                 // 64*128
  int*   idxb = (int*)(kr + 8192);         // 64*4

  proj_kernel<<<216, 256, 0, stream>>>(x, w_qkv, b_qkv, qkv, 384);
  rmean_kernel<<<64, 256, 0, stream>>>(qkv, qr, kr);
  route_kernel<<<64, 64, 0, stream>>>(qr, kr, idxb);
  attn_kernel<<<dim3(64, 8), 512, 0, stream>>>(qkv, idxb, go);
  lepe_kernel<<<dim3(54, 128), 256, 0, stream>>>(qkv + (size_t)256 * S, w_lepe, b_lepe, go);
  proj_kernel<<<216, 256, 0, stream>>>(go, w_out, b_out, out, 128);
}

// Round 14
// 525.657 us; speedup vs baseline: 1.0212x; 1.0212x over previous
//
#include <hip/hip_runtime.h>
#include <math.h>

#define S 13824          // 24*24*24
#define RT 216           // tokens per region (6^3)
#define SCALE 0.08838834764831845f  // 128^-0.5

// ---------------- 1x1 conv (channel matmul): out[o][s] = sum_c w[o][c]*in[c][s] + b[o]
// round-2 proven version: 64-col tiles, 216 blocks, 36us(qkv)/23.5us(out)
__global__ __launch_bounds__(256) void proj_kernel(
    const float* __restrict__ in, const float* __restrict__ w,
    const float* __restrict__ bias, float* __restrict__ outp, int OC) {
  __shared__ float xs[128][64];
  const int tid = threadIdx.x;
  const int sbase = blockIdx.x * 64;
  for (int i = tid; i < 128 * 64; i += 256)
    xs[i >> 6][i & 63] = in[(size_t)(i >> 6) * S + sbase + (i & 63)];
  __syncthreads();
  const int sl = tid & 63;
  const int wv = tid >> 6;
  const int ogN = OC >> 4;
  for (int og = 0; og < ogN; ++og) {
    const int o = og * 16 + wv * 4;
    const float4* w0 = (const float4*)(w + (size_t)o * 128);
    const float4* w1 = w0 + 32;
    const float4* w2 = w0 + 64;
    const float4* w3 = w0 + 96;
    float a0 = 0.f, a1 = 0.f, a2 = 0.f, a3 = 0.f;
#pragma unroll 8
    for (int c4 = 0; c4 < 32; ++c4) {
      float4 f0 = w0[c4], f1 = w1[c4], f2 = w2[c4], f3 = w3[c4];
      float x0 = xs[c4 * 4 + 0][sl], x1 = xs[c4 * 4 + 1][sl];
      float x2 = xs[c4 * 4 + 2][sl], x3 = xs[c4 * 4 + 3][sl];
      a0 += f0.x * x0 + f0.y * x1 + f0.z * x2 + f0.w * x3;
      a1 += f1.x * x0 + f1.y * x1 + f1.z * x2 + f1.w * x3;
      a2 += f2.x * x0 + f2.y * x1 + f2.z * x2 + f2.w * x3;
      a3 += f3.x * x0 + f3.y * x1 + f3.z * x2 + f3.w * x3;
    }
    size_t base = (size_t)o * S + sbase + sl;
    outp[base]         = a0 + bias[o + 0];
    outp[base + S]     = a1 + bias[o + 1];
    outp[base + 2 * S] = a2 + bias[o + 2];
    outp[base + 3 * S] = a3 + bias[o + 3];
  }
}

// ---------------- region means of q and k (deterministic shuffle-tree reduce)
__global__ __launch_bounds__(256) void rmean_kernel(
    const float* __restrict__ qk, float* __restrict__ qr, float* __restrict__ kr) {
  const int n = blockIdx.x;
  const int tid = threadIdx.x, lane = tid & 63, wv = tid >> 6;
  const int rh = (n >> 4) * 6, rw = ((n >> 2) & 3) * 6, rd = (n & 3) * 6;
  int soff[4];
#pragma unroll
  for (int i = 0; i < 4; ++i) {
    int vx = lane + i * 64;
    if (vx < RT) {
      int p = vx / 36, qq = (vx / 6) % 6, u = vx % 6;
      soff[i] = (rh + p) * 576 + (rw + qq) * 24 + (rd + u);
    } else soff[i] = -1;
  }
  for (int ci = 0; ci < 64; ++ci) {
    int ch = wv + ci * 4;  // 0..255
    const float* src = qk + (size_t)ch * S;
    float ssum = 0.f;
#pragma unroll
    for (int i = 0; i < 4; ++i)
      if (soff[i] >= 0) ssum += src[soff[i]];
    for (int off = 32; off > 0; off >>= 1)
      ssum += __shfl_xor(ssum, off);
    if (lane == 0) {
      if (ch < 128) qr[n * 128 + ch] = ssum * (1.f / 216.f);
      else          kr[n * 128 + (ch - 128)] = ssum * (1.f / 216.f);
    }
  }
}

// ---------------- routing: top-4 with low-index tie-break (matches lax.top_k)
__global__ __launch_bounds__(64) void route_kernel(
    const float* __restrict__ qr, const float* __restrict__ kr, int* __restrict__ idxb) {
  const int n = blockIdx.x;
  const int t = threadIdx.x;  // key region
  float acc = 0.f;
  for (int c = 0; c < 128; ++c) acc += qr[n * 128 + c] * kr[t * 128 + c];
  float val = acc;
  int id = t;
  for (int j = 0; j < 4; ++j) {
    float bv = val;
    int bi = id;
    for (int off = 32; off > 0; off >>= 1) {
      float ov = __shfl_xor(bv, off);
      int oi = __shfl_xor(bi, off);
      if (ov > bv || (ov == bv && oi < bi)) { bv = ov; bi = oi; }
    }
    if (t == 0) idxb[n * 4 + j] = bi;
    if (id == bi) val = -INFINITY;
  }
}

// ---------------- attention: one 512-thread block per (region n, head mh).
// bid = n*8 + mh decode with mh = bid&7: consecutive blockIds (-> round-robin
// XCDs) differ in HEAD, so each head's K/V working set (~3.4MB) stays in one
// XCD's 4MB L2 (rounds 4-10: 90MB FETCH from zero L2 reuse).
// Both halves (h = tid>>8) share ONE staged region (34.5KB LDS, single
// buffer); h splits the 216 KEYS (0..107 / 108..215); flash-merge at end.
// Inner loop = round-2-proven serial rare-rescale (44us VALU-busy vs 135us
// for the chunk-4 variant). Staging addresses precomputed into 7 packed
// register slots -> zero div/mod in the hot loop (const-indexed, unrolled).
__global__ __launch_bounds__(512) void attn_kernel(
    const float* __restrict__ qkv, const int* __restrict__ idxb, float* __restrict__ go) {
  __shared__ __align__(16) float ks[RT][20];
  __shared__ __align__(16) float vs[RT][20];
  const float* q = qkv;
  const float* k = qkv + (size_t)128 * S;
  const float* v = qkv + (size_t)256 * S;
  const int bid = blockIdx.x;
  const int n = bid >> 3, mh = bid & 7;
  const int tid = threadIdx.x;
  const int h = tid >> 8;        // key-half (0/1)
  const int qi = tid & 255;      // query token within region
  const int rh = (n >> 4) * 6, rw = ((n >> 2) & 3) * 6, rd = (n & 3) * 6;
  const bool active = qi < RT;

  // precompute staging slots: pack (d<<20)|(t<<12)|poff, poff<4096, t<256, d<16
  int slot[7];
#pragma unroll
  for (int s2 = 0; s2 < 7; ++s2) {
    int i = tid + 512 * s2;
    if (i < RT * 16) {
      int t = i % RT, d = i / RT;
      int p = t / 36, qq = (t / 6) % 6, u = t % 6;
      slot[s2] = (d << 20) | (t << 12) | (p * 576 + qq * 24 + u);
    } else slot[s2] = -1;
  }

  float ql[16];
  int sq = 0;
  if (active) {
    int p = qi / 36, qq = (qi / 6) % 6, u = qi % 6;
    sq = (rh + p) * 576 + (rw + qq) * 24 + (rd + u);
#pragma unroll
    for (int d = 0; d < 16; ++d)
      ql[d] = q[(size_t)(mh * 16 + d) * S + sq] * SCALE;
  }
  float m = -INFINITY, denom = 0.f;
  float o[16];
#pragma unroll
  for (int d = 0; d < 16; ++d) o[d] = 0.f;

  for (int j = 0; j < 4; ++j) {
    const int r = idxb[n * 4 + j];
    const int ghb = (r >> 4) * 3456 + ((r >> 2) & 3) * 144 + (r & 3) * 6;
    __syncthreads();
#pragma unroll
    for (int s2 = 0; s2 < 7; ++s2) {
      int sl = slot[s2];
      if (sl >= 0) {
        int d = sl >> 20, t = (sl >> 12) & 255, poff = sl & 4095;
        size_t gidx = (size_t)(mh * 16 + d) * S + ghb + poff;
        ks[t][d] = k[gidx];
        vs[t][d] = v[gidx];
      }
    }
    __syncthreads();
    if (active) {
      for (int key = h * 108; key < h * 108 + 108; ++key) {
        const float4* kp = (const float4*)&ks[key][0];
        float4 k0 = kp[0], k1 = kp[1], k2 = kp[2], k3 = kp[3];
        float dot = ql[0] * k0.x + ql[1] * k0.y + ql[2] * k0.z + ql[3] * k0.w
                  + ql[4] * k1.x + ql[5] * k1.y + ql[6] * k1.z + ql[7] * k1.w
                  + ql[8] * k2.x + ql[9] * k2.y + ql[10] * k2.z + ql[11] * k2.w
                  + ql[12] * k3.x + ql[13] * k3.y + ql[14] * k3.z + ql[15] * k3.w;
        if (dot > m) {
          float rsc = __expf(m - dot);
          denom *= rsc;
#pragma unroll
          for (int d = 0; d < 16; ++d) o[d] *= rsc;
          m = dot;
        }
        float p = __expf(dot - m);
        denom += p;
        const float4* vp = (const float4*)&vs[key][0];
        float4 v0 = vp[0], v1 = vp[1], v2 = vp[2], v3 = vp[3];
        o[0] += p * v0.x;  o[1] += p * v0.y;  o[2] += p * v0.z;  o[3] += p * v0.w;
        o[4] += p * v1.x;  o[5] += p * v1.y;  o[6] += p * v1.z;  o[7] += p * v1.w;
        o[8] += p * v2.x;  o[9] += p * v2.y;  o[10] += p * v2.z; o[11] += p * v2.w;
        o[12] += p * v3.x; o[13] += p * v3.y; o[14] += p * v3.z; o[15] += p * v3.w;
      }
    }
  }
  // flash-merge the two key-halves (reuse ks storage: 216*18*4 = 15.5KB)
  __syncthreads();
  float* mb = (float*)ks;
  if (h == 1 && active) {
    mb[qi * 18 + 0] = m;
    mb[qi * 18 + 1] = denom;
#pragma unroll
    for (int d = 0; d < 16; ++d) mb[qi * 18 + 2 + d] = o[d];
  }
  __syncthreads();
  if (h == 0 && active) {
    float m1 = mb[qi * 18 + 0], d1 = mb[qi * 18 + 1];
    float M = fmaxf(m, m1);
    float s0 = __expf(m - M), s1 = __expf(m1 - M);
    float inv = 1.f / (denom * s0 + d1 * s1);
#pragma unroll
    for (int d = 0; d < 16; ++d)
      go[(size_t)(mh * 16 + d) * S + sq] = (o[d] * s0 + mb[qi * 18 + 2 + d] * s1) * inv;
  }
}

// ---------------- lepe: depthwise 3x3x3 conv on v, accumulated into go
// round-2 proven version (16.8us)
__global__ __launch_bounds__(256) void lepe_kernel(
    const float* __restrict__ v, const float* __restrict__ wl,
    const float* __restrict__ bl, float* __restrict__ go) {
  const int c = blockIdx.y;
  const int s = blockIdx.x * 256 + threadIdx.x;
  const int h = s / 576, w = (s / 24) % 24, d = s % 24;
  const float* vp = v + (size_t)c * S;
  float wreg[27];
#pragma unroll
  for (int i = 0; i < 27; ++i) wreg[i] = wl[c * 27 + i];
  float acc = bl[c];
#pragma unroll
  for (int a = 0; a < 3; ++a) {
    int hh = h + a - 1;
    if (hh < 0 || hh >= 24) continue;
#pragma unroll
    for (int b = 0; b < 3; ++b) {
      int ww = w + b - 1;
      if (ww < 0 || ww >= 24) continue;
#pragma unroll
      for (int e = 0; e < 3; ++e) {
        int dd = d + e - 1;
        if (dd < 0 || dd >= 24) continue;
        acc += vp[hh * 576 + ww * 24 + dd] * wreg[a * 9 + b * 3 + e];
      }
    }
  }
  go[(size_t)c * S + s] += acc;
}

extern "C" void kernel_launch(void* const* d_in, const int* in_sizes, int n_in,
                              void* d_out, int out_size, void* d_ws, size_t ws_size,
                              hipStream_t stream) {
  const float* x      = (const float*)d_in[0];
  const float* w_qkv  = (const float*)d_in[1];
  const float* b_qkv  = (const float*)d_in[2];
  const float* w_lepe = (const float*)d_in[3];
  const float* b_lepe = (const float*)d_in[4];
  const float* w_out  = (const float*)d_in[5];
  const float* b_out  = (const float*)d_in[6];
  float* out = (float*)d_out;
  float* ws  = (float*)d_ws;

  float* qkv  = ws;                        // 384*13824
  float* go   = qkv + (size_t)384 * S;     // 128*13824
  float* qr   = go + (size_t)128 * S;      // 64*128
  float* kr   = qr + 8192;                 // 64*128
  int*   idxb = (int*)(kr + 8192);         // 64*4

  proj_kernel<<<216, 256, 0, stream>>>(x, w_qkv, b_qkv, qkv, 384);
  rmean_kernel<<<64, 256, 0, stream>>>(qkv, qr, kr);
  route_kernel<<<64, 64, 0, stream>>>(qr, kr, idxb);
  attn_kernel<<<512, 512, 0, stream>>>(qkv, idxb, go);
  lepe_kernel<<<dim3(54, 128), 256, 0, stream>>>(qkv + (size_t)256 * S, w_lepe, b_lepe, go);
  proj_kernel<<<216, 256, 0, stream>>>(go, w_out, b_out, out, 128);
}

// Round 15
// 452.106 us; speedup vs baseline: 1.1873x; 1.1627x over previous
//
#include <hip/hip_runtime.h>
#include <math.h>

#define S 13824          // 24*24*24
#define RT 216           // tokens per region (6^3)
#define SCALE 0.08838834764831845f  // 128^-0.5

// ---------------- 1x1 conv (channel matmul): out[o][s] = sum_c w[o][c]*in[c][s] + b[o]
// v2: 8 rows x 2 cols per thread -> 64 FMA : 16 loads (v1 was 16:8).
// Weight-row addresses are wave-uniform -> scalar loads; x reads are float2 LDS.
__global__ __launch_bounds__(256) void proj_kernel(
    const float* __restrict__ in, const float* __restrict__ w,
    const float* __restrict__ bias, float* __restrict__ outp, int OC) {
  __shared__ float xs[128][64];
  const int tid = threadIdx.x;
  const int sbase = blockIdx.x * 64;
  for (int i = tid; i < 128 * 64; i += 256)
    xs[i >> 6][i & 63] = in[(size_t)(i >> 6) * S + sbase + (i & 63)];
  __syncthreads();
  const int sl = (tid & 31) * 2;   // columns sl, sl+1
  const int wv = tid >> 5;         // 0..7 -> 8 rows each (64 rows per pass)
  const int passes = OC >> 6;
  for (int pg = 0; pg < passes; ++pg) {
    const int o = pg * 64 + wv * 8;
    float a[8][2];
#pragma unroll
    for (int r = 0; r < 8; ++r) { a[r][0] = 0.f; a[r][1] = 0.f; }
#pragma unroll 4
    for (int c4 = 0; c4 < 32; ++c4) {
      float2 x0 = *(const float2*)&xs[c4 * 4 + 0][sl];
      float2 x1 = *(const float2*)&xs[c4 * 4 + 1][sl];
      float2 x2 = *(const float2*)&xs[c4 * 4 + 2][sl];
      float2 x3 = *(const float2*)&xs[c4 * 4 + 3][sl];
#pragma unroll
      for (int r = 0; r < 8; ++r) {
        float4 f = ((const float4*)(w + (size_t)(o + r) * 128))[c4];
        a[r][0] += f.x * x0.x + f.y * x1.x + f.z * x2.x + f.w * x3.x;
        a[r][1] += f.x * x0.y + f.y * x1.y + f.z * x2.y + f.w * x3.y;
      }
    }
#pragma unroll
    for (int r = 0; r < 8; ++r) {
      size_t base = (size_t)(o + r) * S + sbase + sl;
      float b = bias[o + r];
      outp[base]     = a[r][0] + b;
      outp[base + 1] = a[r][1] + b;
    }
  }
}

// ---------------- region means of q and k (deterministic shuffle-tree reduce)
__global__ __launch_bounds__(256) void rmean_kernel(
    const float* __restrict__ qk, float* __restrict__ qr, float* __restrict__ kr) {
  const int n = blockIdx.x;
  const int tid = threadIdx.x, lane = tid & 63, wv = tid >> 6;
  const int rh = (n >> 4) * 6, rw = ((n >> 2) & 3) * 6, rd = (n & 3) * 6;
  int soff[4];
#pragma unroll
  for (int i = 0; i < 4; ++i) {
    int vx = lane + i * 64;
    if (vx < RT) {
      int p = vx / 36, qq = (vx / 6) % 6, u = vx % 6;
      soff[i] = (rh + p) * 576 + (rw + qq) * 24 + (rd + u);
    } else soff[i] = -1;
  }
  for (int ci = 0; ci < 64; ++ci) {
    int ch = wv + ci * 4;  // 0..255
    const float* src = qk + (size_t)ch * S;
    float ssum = 0.f;
#pragma unroll
    for (int i = 0; i < 4; ++i)
      if (soff[i] >= 0) ssum += src[soff[i]];
    for (int off = 32; off > 0; off >>= 1)
      ssum += __shfl_xor(ssum, off);
    if (lane == 0) {
      if (ch < 128) qr[n * 128 + ch] = ssum * (1.f / 216.f);
      else          kr[n * 128 + (ch - 128)] = ssum * (1.f / 216.f);
    }
  }
}

// ---------------- routing: top-4 with low-index tie-break (matches lax.top_k)
__global__ __launch_bounds__(64) void route_kernel(
    const float* __restrict__ qr, const float* __restrict__ kr, int* __restrict__ idxb) {
  const int n = blockIdx.x;
  const int t = threadIdx.x;  // key region
  float acc = 0.f;
  for (int c = 0; c < 128; ++c) acc += qr[n * 128 + c] * kr[t * 128 + c];
  float val = acc;
  int id = t;
  for (int j = 0; j < 4; ++j) {
    float bv = val;
    int bi = id;
    for (int off = 32; off > 0; off >>= 1) {
      float ov = __shfl_xor(bv, off);
      int oi = __shfl_xor(bi, off);
      if (ov > bv || (ov == bv && oi < bi)) { bv = ov; bi = oi; }
    }
    if (t == 0) idxb[n * 4 + j] = bi;
    if (id == bi) val = -INFINITY;
  }
}

// ---------------- attention: UNCHANGED from round 14 (measured: 173us, FETCH 10.4MB,
// VGPR 52, control group for this round).
__global__ __launch_bounds__(512) void attn_kernel(
    const float* __restrict__ qkv, const int* __restrict__ idxb, float* __restrict__ go) {
  __shared__ __align__(16) float ks[RT][20];
  __shared__ __align__(16) float vs[RT][20];
  const float* q = qkv;
  const float* k = qkv + (size_t)128 * S;
  const float* v = qkv + (size_t)256 * S;
  const int bid = blockIdx.x;
  const int n = bid >> 3, mh = bid & 7;
  const int tid = threadIdx.x;
  const int h = tid >> 8;        // key-half (0/1)
  const int qi = tid & 255;      // query token within region
  const int rh = (n >> 4) * 6, rw = ((n >> 2) & 3) * 6, rd = (n & 3) * 6;
  const bool active = qi < RT;

  int slot[7];
#pragma unroll
  for (int s2 = 0; s2 < 7; ++s2) {
    int i = tid + 512 * s2;
    if (i < RT * 16) {
      int t = i % RT, d = i / RT;
      int p = t / 36, qq = (t / 6) % 6, u = t % 6;
      slot[s2] = (d << 20) | (t << 12) | (p * 576 + qq * 24 + u);
    } else slot[s2] = -1;
  }

  float ql[16];
  int sq = 0;
  if (active) {
    int p = qi / 36, qq = (qi / 6) % 6, u = qi % 6;
    sq = (rh + p) * 576 + (rw + qq) * 24 + (rd + u);
#pragma unroll
    for (int d = 0; d < 16; ++d)
      ql[d] = q[(size_t)(mh * 16 + d) * S + sq] * SCALE;
  }
  float m = -INFINITY, denom = 0.f;
  float o[16];
#pragma unroll
  for (int d = 0; d < 16; ++d) o[d] = 0.f;

  for (int j = 0; j < 4; ++j) {
    const int r = idxb[n * 4 + j];
    const int ghb = (r >> 4) * 3456 + ((r >> 2) & 3) * 144 + (r & 3) * 6;
    __syncthreads();
#pragma unroll
    for (int s2 = 0; s2 < 7; ++s2) {
      int sl = slot[s2];
      if (sl >= 0) {
        int d = sl >> 20, t = (sl >> 12) & 255, poff = sl & 4095;
        size_t gidx = (size_t)(mh * 16 + d) * S + ghb + poff;
        ks[t][d] = k[gidx];
        vs[t][d] = v[gidx];
      }
    }
    __syncthreads();
    if (active) {
      for (int key = h * 108; key < h * 108 + 108; ++key) {
        const float4* kp = (const float4*)&ks[key][0];
        float4 k0 = kp[0], k1 = kp[1], k2 = kp[2], k3 = kp[3];
        float dot = ql[0] * k0.x + ql[1] * k0.y + ql[2] * k0.z + ql[3] * k0.w
                  + ql[4] * k1.x + ql[5] * k1.y + ql[6] * k1.z + ql[7] * k1.w
                  + ql[8] * k2.x + ql[9] * k2.y + ql[10] * k2.z + ql[11] * k2.w
                  + ql[12] * k3.x + ql[13] * k3.y + ql[14] * k3.z + ql[15] * k3.w;
        if (dot > m) {
          float rsc = __expf(m - dot);
          denom *= rsc;
#pragma unroll
          for (int d = 0; d < 16; ++d) o[d] *= rsc;
          m = dot;
        }
        float p = __expf(dot - m);
        denom += p;
        const float4* vp = (const float4*)&vs[key][0];
        float4 v0 = vp[0], v1 = vp[1], v2 = vp[2], v3 = vp[3];
        o[0] += p * v0.x;  o[1] += p * v0.y;  o[2] += p * v0.z;  o[3] += p * v0.w;
        o[4] += p * v1.x;  o[5] += p * v1.y;  o[6] += p * v1.z;  o[7] += p * v1.w;
        o[8] += p * v2.x;  o[9] += p * v2.y;  o[10] += p * v2.z; o[11] += p * v2.w;
        o[12] += p * v3.x; o[13] += p * v3.y; o[14] += p * v3.z; o[15] += p * v3.w;
      }
    }
  }
  __syncthreads();
  float* mb = (float*)ks;
  if (h == 1 && active) {
    mb[qi * 18 + 0] = m;
    mb[qi * 18 + 1] = denom;
#pragma unroll
    for (int d = 0; d < 16; ++d) mb[qi * 18 + 2 + d] = o[d];
  }
  __syncthreads();
  if (h == 0 && active) {
    float m1 = mb[qi * 18 + 0], d1 = mb[qi * 18 + 1];
    float M = fmaxf(m, m1);
    float s0 = __expf(m - M), s1 = __expf(m1 - M);
    float inv = 1.f / (denom * s0 + d1 * s1);
#pragma unroll
    for (int d = 0; d < 16; ++d)
      go[(size_t)(mh * 16 + d) * S + sq] = (o[d] * s0 + mb[qi * 18 + 2 + d] * s1) * inv;
  }
}

// ---------------- lepe v2: depthwise 3x3x3, one d-row per thread with a sliding
// 9x3 window: 9 loads + 27 FMA per output (v1: 27 loads + 27 FMA).
// grid dim3(3, 128), block 192: thread -> (h,w), serial over d.
__global__ __launch_bounds__(192) void lepe_kernel(
    const float* __restrict__ v, const float* __restrict__ wl,
    const float* __restrict__ bl, float* __restrict__ go) {
  const int c = blockIdx.y;
  const int hw = blockIdx.x * 192 + threadIdx.x;  // 0..575
  const int h = hw / 24, w = hw % 24;
  const float* vp = v + (size_t)c * S;
  float wreg[27];
#pragma unroll
  for (int i = 0; i < 27; ++i) wreg[i] = wl[c * 27 + i];
  const float bc = bl[c];
  float win[9][3];
#pragma unroll
  for (int ab = 0; ab < 9; ++ab) {
    int hh = h + ab / 3 - 1, ww = w + ab % 3 - 1;
    bool ok = (hh >= 0 && hh < 24 && ww >= 0 && ww < 24);
    const float* rp = vp + hh * 576 + ww * 24;
    win[ab][0] = 0.f;                     // d = -1
    win[ab][1] = ok ? rp[0] : 0.f;        // d = 0
    win[ab][2] = ok ? rp[1] : 0.f;        // d = 1
  }
  size_t obase = (size_t)c * S + h * 576 + w * 24;
  for (int d = 0; d < 24; ++d) {
    float acc = bc;
#pragma unroll
    for (int ab = 0; ab < 9; ++ab)
      acc += win[ab][0] * wreg[ab * 3 + 0]
           + win[ab][1] * wreg[ab * 3 + 1]
           + win[ab][2] * wreg[ab * 3 + 2];
    go[obase + d] += acc;
    int nd = d + 2;
#pragma unroll
    for (int ab = 0; ab < 9; ++ab) {
      win[ab][0] = win[ab][1];
      win[ab][1] = win[ab][2];
      int hh = h + ab / 3 - 1, ww = w + ab % 3 - 1;
      bool ok = (hh >= 0 && hh < 24 && ww >= 0 && ww < 24 && nd < 24);
      win[ab][2] = ok ? vp[hh * 576 + ww * 24 + nd] : 0.f;
    }
  }
}

extern "C" void kernel_launch(void* const* d_in, const int* in_sizes, int n_in,
                              void* d_out, int out_size, void* d_ws, size_t ws_size,
                              hipStream_t stream) {
  const float* x      = (const float*)d_in[0];
  const float* w_qkv  = (const float*)d_in[1];
  const float* b_qkv  = (const float*)d_in[2];
  const float* w_lepe = (const float*)d_in[3];
  const float* b_lepe = (const float*)d_in[4];
  const float* w_out  = (const float*)d_in[5];
  const float* b_out  = (const float*)d_in[6];
  float* out = (float*)d_out;
  float* ws  = (float*)d_ws;

  float* qkv  = ws;                        // 384*13824
  float* go   = qkv + (size_t)384 * S;     // 128*13824
  float* qr   = go + (size_t)128 * S;      // 64*128
  float* kr   = qr + 8192;                 // 64*128
  int*   idxb = (int*)(kr + 8192);         // 64*4

  proj_kernel<<<216, 256, 0, stream>>>(x, w_qkv, b_qkv, qkv, 384);
  rmean_kernel<<<64, 256, 0, stream>>>(qkv, qr, kr);
  route_kernel<<<64, 64, 0, stream>>>(qr, kr, idxb);
  attn_kernel<<<512, 512, 0, stream>>>(qkv, idxb, go);
  lepe_kernel<<<dim3(3, 128), 192, 0, stream>>>(qkv + (size_t)256 * S, w_lepe, b_lepe, go);
  proj_kernel<<<216, 256, 0, stream>>>(go, w_out, b_out, out, 128);
}